// Round 12
// baseline (1334.922 us; speedup 1.0000x reference)
//
#include <hip/hip_runtime.h>
#include <cstdint>
#include <cmath>

#define U_ 40000
#define I_ 40000
#define C_ 5
#define D_ 128
#define A_ 64
#define L_ 2
#define E_ 1280000
#define N_ (U_ + I_)
#define BINS_ (N_ * C_)
#define NEDGE_ (C_ * E_)                      // 6,400,000
#define EPB_ 4096
#define NBRX_ ((NEDGE_ + EPB_ - 1) / EPB_)    // 1563
#define ND1_ 1024
#define ND2_ 512

typedef __attribute__((ext_vector_type(8))) short short8;
typedef __attribute__((ext_vector_type(4))) short short4v;
typedef __attribute__((ext_vector_type(4))) float f32x4;

static __device__ __forceinline__ short f2bf(float f) {
    union { float f; uint32_t u; } x; x.f = f;
    uint32_t u = x.u;
    uint32_t r = (u + 0x7fffu + ((u >> 16) & 1u)) >> 16;   // RNE
    return (short)r;
}

// ---------------------------------------------------------------------------
// init: egob = bf16(concat(user, item))
// ---------------------------------------------------------------------------
__global__ __launch_bounds__(256) void init_kernel(
    const float* __restrict__ user, const float* __restrict__ item,
    short* __restrict__ egob)
{
    size_t i = (size_t)blockIdx.x * 256 + threadIdx.x;    // 8-float index
    const size_t total8 = (size_t)N_ * C_ * D_ / 8;
    const size_t user4  = (size_t)U_ * C_ * D_ / 4;
    if (i < total8) {
        size_t f4 = 2 * i;
        const float4* src = (f4 < user4) ? (const float4*)user
                                         : (const float4*)item - user4;
        float4 x0 = src[f4], x1 = src[f4 + 1];
        short8 p;
        p[0] = f2bf(x0.x); p[1] = f2bf(x0.y); p[2] = f2bf(x0.z); p[3] = f2bf(x0.w);
        p[4] = f2bf(x1.x); p[5] = f2bf(x1.y); p[6] = f2bf(x1.z); p[7] = f2bf(x1.w);
        ((short8*)egob)[i] = p;
    }
}

// ---------------------------------------------------------------------------
// crit chain + zero pad row of d_out
// ---------------------------------------------------------------------------
__global__ __launch_bounds__(128) void crit_kernel(
    const float* __restrict__ crit0, const float* __restrict__ clayers,
    float* __restrict__ crit1, float* __restrict__ crit2,
    float* __restrict__ crit_means, float* __restrict__ padrow)
{
    __shared__ float c0[C_ * D_], c1[C_ * D_], c2[C_ * D_];
    int t = threadIdx.x;
    for (int i = t; i < C_ * D_; i += 128) { c0[i] = crit0[i]; padrow[i] = 0.f; }
    __syncthreads();
    for (int c = 0; c < C_; ++c) {
        float acc = 0.f;
        for (int d = 0; d < D_; ++d) acc = fmaf(c0[c * D_ + d], clayers[d * D_ + t], acc);
        c1[c * D_ + t] = acc;
    }
    __syncthreads();
    for (int c = 0; c < C_; ++c) {
        float acc = 0.f;
        for (int d = 0; d < D_; ++d) acc = fmaf(c1[c * D_ + d], clayers[D_ * D_ + d * D_ + t], acc);
        c2[c * D_ + t] = acc;
    }
    __syncthreads();
    for (int i = t; i < C_ * D_; i += 128) {
        crit1[i] = c1[i];
        crit2[i] = c2[i];
        crit_means[i] = (c0[i] + c1[i] + c2[i]) * (1.0f / 3.0f);
    }
}

// ---------------------------------------------------------------------------
// prepack W / G0 / G1 into bf16 B-fragment layout (mfma_f32_16x16x32_bf16)
// ---------------------------------------------------------------------------
__global__ __launch_bounds__(256) void prepack_kernel(
    const float* __restrict__ W, const float* __restrict__ gl,
    short* __restrict__ Wf, short* __restrict__ Gf)
{
    int b = blockIdx.x;               // 0..23: matrix = b>>3, t = b&7
    int m = b >> 3, t = b & 7;
    int q = threadIdx.x >> 6, l = threadIdx.x & 63;
    int g = l >> 4, c15 = l & 15;
    const float* src = (m == 0) ? W : gl + (size_t)(m - 1) * D_ * D_;
    short*       dst = (m == 0) ? Wf : Gf + (size_t)(m - 1) * D_ * D_;
    short8 v;
    #pragma unroll
    for (int j = 0; j < 8; ++j) {
        int k = q * 32 + g * 8 + j;
        int n = t * 16 + c15;
        v[j] = f2bf(src[k * D_ + n]);
    }
    *(short8*)(dst + (((t * 4 + q) * 64 + l) << 3)) = v;
}

// ---------------------------------------------------------------------------
// prepack p1 (C,D,A) as B-frags of P1all (128 x 320)
// ---------------------------------------------------------------------------
__global__ __launch_bounds__(64) void prepack_p1_kernel(
    const float* __restrict__ p1, short* __restrict__ P1f)
{
    int t = blockIdx.x >> 2, q = blockIdx.x & 3;   // 80 blocks
    int lane = threadIdx.x;
    int g = lane >> 4, c15 = lane & 15;
    int k = t >> 2, a = (t & 3) * 16 + c15;
    short8 v;
    #pragma unroll
    for (int j = 0; j < 8; ++j) {
        int d = q * 32 + g * 8 + j;
        v[j] = f2bf(p1[((size_t)k * D_ + d) * A_ + a]);
    }
    *(short8*)(P1f + (((t * 4 + q) * 64 + lane) << 3)) = v;
}

// ===========================================================================
// CSR build via 2-pass LSD radix sort (no global atomics)
// key = bin' = c*N + row (c-major). pass1: low 10 bits (non-stable),
// pass2: high 9 bits (stable via ballot ranks). Then boundary -> bin_start.
// ===========================================================================

__global__ __launch_bounds__(256) void p1_count_kernel(
    const int* __restrict__ rows, int* __restrict__ ghistT)
{
    __shared__ int h[ND1_];
    int b = blockIdx.x, tid = threadIdx.x;
    for (int i = tid; i < ND1_; i += 256) h[i] = 0;
    __syncthreads();
    int base = b * EPB_;
    for (int ch = 0; ch < EPB_ / 256; ++ch) {
        int eid = base + ch * 256 + tid;
        if (eid < NEDGE_) {
            int key = (eid / E_) * N_ + rows[eid];
            atomicAdd(&h[key & (ND1_ - 1)], 1);
        }
    }
    __syncthreads();
    for (int i = tid; i < ND1_; i += 256) ghistT[b * ND1_ + i] = h[i];
}

__global__ __launch_bounds__(256) void transpose_kernel(
    const int* __restrict__ src, int* __restrict__ dst, int R, int Cc)
{
    int i = blockIdx.x * 256 + threadIdx.x;
    if (i < R * Cc) { int r = i / Cc, c = i % Cc; dst[c * R + r] = src[i]; }
}

__global__ __launch_bounds__(256) void scanA_g(
    const int* __restrict__ src, int* __restrict__ dst,
    int* __restrict__ bsum, int n)
{
    __shared__ int ls[256];
    int b = blockIdx.x, t = threadIdx.x;
    int base = b * 1024 + t * 4;
    int v[4];
    #pragma unroll
    for (int i = 0; i < 4; ++i) v[i] = (base + i < n) ? src[base + i] : 0;
    int s = v[0] + v[1] + v[2] + v[3];
    ls[t] = s;
    __syncthreads();
    for (int off = 1; off < 256; off <<= 1) {
        int x = (t >= off) ? ls[t - off] : 0;
        __syncthreads();
        ls[t] += x;
        __syncthreads();
    }
    int excl = ls[t] - s;
    if (t == 255) bsum[b] = ls[255];
    #pragma unroll
    for (int i = 0; i < 4; ++i) {
        if (base + i < n) dst[base + i] = excl;
        excl += v[i];
    }
}

__global__ __launch_bounds__(256) void scanB_g(int* __restrict__ bsum, int nb)
{
    __shared__ int ls[256];
    int t = threadIdx.x;
    int v[8]; int s = 0;
    #pragma unroll
    for (int i = 0; i < 8; ++i) {
        int idx = t * 8 + i;
        v[i] = (idx < nb) ? bsum[idx] : 0;
        s += v[i];
    }
    ls[t] = s;
    __syncthreads();
    for (int off = 1; off < 256; off <<= 1) {
        int x = (t >= off) ? ls[t - off] : 0;
        __syncthreads();
        ls[t] += x;
        __syncthreads();
    }
    int excl = ls[t] - s;
    #pragma unroll
    for (int i = 0; i < 8; ++i) {
        int idx = t * 8 + i;
        if (idx < nb) bsum[idx] = excl;
        excl += v[i];
    }
}

__global__ __launch_bounds__(256) void scanC_g(
    int* __restrict__ dst, const int* __restrict__ bsum, int n)
{
    int b = blockIdx.x, t = threadIdx.x;
    int off = bsum[b];
    int base = b * 1024 + t * 4;
    #pragma unroll
    for (int i = 0; i < 4; ++i)
        if (base + i < n) dst[base + i] += off;
}

__global__ __launch_bounds__(256) void p1_place_kernel(
    const int* __restrict__ rows, const float* __restrict__ vals,
    const int* __restrict__ cols, const int* __restrict__ gbaseT,
    int* __restrict__ keyA, uint2* __restrict__ vcA)
{
    __shared__ int cur[ND1_];
    __shared__ int bst[ND1_];
    __shared__ int gb[ND1_];
    __shared__ int ts[256];
    __shared__ int sK[EPB_];
    __shared__ uint2 sV[EPB_];
    int b = blockIdx.x, tid = threadIdx.x;
    for (int i = tid; i < ND1_; i += 256) { cur[i] = 0; gb[i] = gbaseT[b * ND1_ + i]; }
    __syncthreads();
    int base = b * EPB_;
    for (int ch = 0; ch < EPB_ / 256; ++ch) {
        int eid = base + ch * 256 + tid;
        if (eid < NEDGE_) {
            int key = (eid / E_) * N_ + rows[eid];
            atomicAdd(&cur[key & (ND1_ - 1)], 1);
        }
    }
    __syncthreads();
    {
        int v[4]; int s = 0;
        #pragma unroll
        for (int i = 0; i < 4; ++i) { v[i] = cur[tid * 4 + i]; s += v[i]; }
        ts[tid] = s;
        __syncthreads();
        for (int off = 1; off < 256; off <<= 1) {
            int x = (tid >= off) ? ts[tid - off] : 0;
            __syncthreads();
            ts[tid] += x;
            __syncthreads();
        }
        int excl = ts[tid] - s;
        #pragma unroll
        for (int i = 0; i < 4; ++i) { bst[tid * 4 + i] = excl; excl += v[i]; }
        __syncthreads();
        #pragma unroll
        for (int i = 0; i < 4; ++i) cur[tid * 4 + i] = bst[tid * 4 + i];
    }
    __syncthreads();
    for (int ch = 0; ch < EPB_ / 256; ++ch) {
        int eid = base + ch * 256 + tid;
        if (eid < NEDGE_) {
            int key = (eid / E_) * N_ + rows[eid];
            int d = key & (ND1_ - 1);
            int p = atomicAdd(&cur[d], 1);
            sK[p] = key;
            union { float f; uint32_t u; } t; t.f = vals[eid];
            uint2 m; m.x = t.u; m.y = (uint32_t)cols[eid];
            sV[p] = m;
        }
    }
    __syncthreads();
    int M = NEDGE_ - base; if (M > EPB_) M = EPB_;
    for (int i = tid; i < M; i += 256) {
        int key = sK[i]; int d = key & (ND1_ - 1);
        int pos = gb[d] + (i - bst[d]);
        keyA[pos] = key; vcA[pos] = sV[i];
    }
}

__global__ __launch_bounds__(256) void p2_count_kernel(
    const int* __restrict__ keyA, int* __restrict__ ghistT)
{
    __shared__ int h[ND2_];
    int b = blockIdx.x, tid = threadIdx.x;
    for (int i = tid; i < ND2_; i += 256) h[i] = 0;
    __syncthreads();
    int base = b * EPB_;
    for (int ch = 0; ch < EPB_ / 256; ++ch) {
        int eid = base + ch * 256 + tid;
        if (eid < NEDGE_) atomicAdd(&h[keyA[eid] >> 10], 1);
    }
    __syncthreads();
    for (int i = tid; i < ND2_; i += 256) ghistT[b * ND2_ + i] = h[i];
}

__global__ __launch_bounds__(256) void p2_place_kernel(
    const int* __restrict__ keyA, const uint2* __restrict__ vcA,
    const int* __restrict__ gbaseT,
    int* __restrict__ keyB, uint2* __restrict__ vcB)
{
    __shared__ int cur[ND2_];
    __shared__ int bst[ND2_];
    __shared__ int gb[ND2_];
    __shared__ int wh[4 * ND2_];
    __shared__ int ts[256];
    __shared__ int sK[EPB_];
    __shared__ uint2 sV[EPB_];
    int b = blockIdx.x, tid = threadIdx.x;
    int lane = tid & 63, wv = tid >> 6;
    for (int i = tid; i < ND2_; i += 256) { cur[i] = 0; gb[i] = gbaseT[b * ND2_ + i]; }
    __syncthreads();
    int base = b * EPB_;
    for (int ch = 0; ch < EPB_ / 256; ++ch) {
        int eid = base + ch * 256 + tid;
        if (eid < NEDGE_) atomicAdd(&cur[keyA[eid] >> 10], 1);
    }
    __syncthreads();
    {
        int v0 = cur[tid * 2], v1 = cur[tid * 2 + 1];
        int s = v0 + v1;
        ts[tid] = s;
        __syncthreads();
        for (int off = 1; off < 256; off <<= 1) {
            int x = (tid >= off) ? ts[tid - off] : 0;
            __syncthreads();
            ts[tid] += x;
            __syncthreads();
        }
        int excl = ts[tid] - s;
        bst[tid * 2] = excl; bst[tid * 2 + 1] = excl + v0;
        __syncthreads();
        cur[tid * 2] = bst[tid * 2]; cur[tid * 2 + 1] = bst[tid * 2 + 1];
    }
    __syncthreads();
    for (int ch = 0; ch < EPB_ / 256; ++ch) {
        for (int i = tid; i < 4 * ND2_; i += 256) wh[i] = 0;
        __syncthreads();
        int eid = base + ch * 256 + tid;
        bool valid = eid < NEDGE_;
        int key = 0, d = 0; uint2 v = make_uint2(0u, 0u);
        if (valid) { key = keyA[eid]; v = vcA[eid]; d = key >> 10; }
        unsigned long long m = __ballot(valid ? 1 : 0);
        #pragma unroll
        for (int bit = 0; bit < 9; ++bit) {
            unsigned long long bb = __ballot((valid && ((d >> bit) & 1)) ? 1 : 0);
            m &= ((d >> bit) & 1) ? bb : ~bb;
        }
        unsigned long long ltm = ((unsigned long long)1 << lane) - 1;
        int rw = __popcll(m & ltm);
        int cnt = __popcll(m);
        if (valid && rw == 0) wh[wv * ND2_ + d] = cnt;
        __syncthreads();
        if (valid) {
            int off = 0;
            for (int w2 = 0; w2 < wv; ++w2) off += wh[w2 * ND2_ + d];
            int p = cur[d] + off + rw;
            sK[p] = key; sV[p] = v;
        }
        __syncthreads();
        for (int i = tid; i < ND2_; i += 256)
            cur[i] += wh[i] + wh[ND2_ + i] + wh[2 * ND2_ + i] + wh[3 * ND2_ + i];
        __syncthreads();
    }
    int M = NEDGE_ - base; if (M > EPB_) M = EPB_;
    for (int i = tid; i < M; i += 256) {
        int key = sK[i]; int d = key >> 10;
        int pos = gb[d] + (i - bst[d]);
        keyB[pos] = key; vcB[pos] = sV[i];
    }
}

__global__ __launch_bounds__(256) void boundary_kernel(
    const int* __restrict__ keyB, int* __restrict__ bin_start)
{
    int i = blockIdx.x * 256 + threadIdx.x;
    if (i >= NEDGE_) return;
    int k = keyB[i];
    if (i == 0) {
        for (int b = 0; b <= k; ++b) bin_start[b] = 0;
    } else {
        int kp = keyB[i - 1];
        for (int b = kp + 1; b <= k; ++b) bin_start[b] = i;
    }
    if (i == NEDGE_ - 1) {
        for (int b = k + 1; b <= BINS_; ++b) bin_start[b] = NEDGE_;
    }
}

// ---------------------------------------------------------------------------
// gather (bf16) quarter-wave, shfl-free: each 16-lane quarter owns one edge,
// loads its (val,col) directly (same-address broadcast within quarter, vc is
// streamed so L1/L2-hot). Main loop keeps 4 vc + 4 ego loads in flight.
// ---------------------------------------------------------------------------
__global__ __launch_bounds__(256) void gather_kernel(
    const uint4* __restrict__ eg128, const uint2* __restrict__ vc,
    const int* __restrict__ bin_start, uint4* __restrict__ gfb128)
{
    int w = (int)(((size_t)blockIdx.x * 256 + threadIdx.x) >> 6);
    int lane = threadIdx.x & 63;
    w = __builtin_amdgcn_readfirstlane(w);
    int bs = bin_start[w], be = bin_start[w + 1];
    int c = w / N_;
    int row = w - c * N_;
    int q4 = lane >> 4, l15 = lane & 15;
    float a0 = 0.f, a1 = 0.f, a2 = 0.f, a3 = 0.f;
    float a4 = 0.f, a5 = 0.f, a6 = 0.f, a7 = 0.f;

    union { uint32_t u; float f; } t;
    #define ACC8(mm, vv) \
        t.u = mm.x << 16;         a0 = fmaf(vv, t.f, a0); \
        t.u = mm.x & 0xffff0000u; a1 = fmaf(vv, t.f, a1); \
        t.u = mm.y << 16;         a2 = fmaf(vv, t.f, a2); \
        t.u = mm.y & 0xffff0000u; a3 = fmaf(vv, t.f, a3); \
        t.u = mm.z << 16;         a4 = fmaf(vv, t.f, a4); \
        t.u = mm.z & 0xffff0000u; a5 = fmaf(vv, t.f, a5); \
        t.u = mm.w << 16;         a6 = fmaf(vv, t.f, a6); \
        t.u = mm.w & 0xffff0000u; a7 = fmaf(vv, t.f, a7);

    int j = bs;
    for (; j + 16 <= be; j += 16) {          // 16 edges: 4 vc + 4 ego loads in flight
        uint2 eA = vc[j + q4];
        uint2 eB = vc[j + 4 + q4];
        uint2 eC = vc[j + 8 + q4];
        uint2 eD = vc[j + 12 + q4];
        uint4 mA = eg128[((size_t)(int)eA.y * C_ + c) * (D_ / 8) + l15];
        uint4 mB = eg128[((size_t)(int)eB.y * C_ + c) * (D_ / 8) + l15];
        uint4 mC = eg128[((size_t)(int)eC.y * C_ + c) * (D_ / 8) + l15];
        uint4 mD = eg128[((size_t)(int)eD.y * C_ + c) * (D_ / 8) + l15];
        union { uint32_t u; float f; } fv;
        fv.u = eA.x; float vA = fv.f;
        fv.u = eB.x; float vB = fv.f;
        fv.u = eC.x; float vC = fv.f;
        fv.u = eD.x; float vD = fv.f;
        ACC8(mA, vA) ACC8(mB, vB) ACC8(mC, vC) ACC8(mD, vD)
    }
    for (; j < be; j += 4) {                 // tail: guarded quarter-step
        int idx = j + q4;
        bool act = idx < be;
        uint2 e0 = vc[act ? idx : be - 1];
        union { uint32_t u; float f; } fv; fv.u = e0.x;
        float v0 = act ? fv.f : 0.f;
        uint4 m0 = eg128[((size_t)(int)e0.y * C_ + c) * (D_ / 8) + l15];
        ACC8(m0, v0)
    }
    #undef ACC8

    a0 += __shfl_xor(a0, 16); a1 += __shfl_xor(a1, 16);
    a2 += __shfl_xor(a2, 16); a3 += __shfl_xor(a3, 16);
    a4 += __shfl_xor(a4, 16); a5 += __shfl_xor(a5, 16);
    a6 += __shfl_xor(a6, 16); a7 += __shfl_xor(a7, 16);
    a0 += __shfl_xor(a0, 32); a1 += __shfl_xor(a1, 32);
    a2 += __shfl_xor(a2, 32); a3 += __shfl_xor(a3, 32);
    a4 += __shfl_xor(a4, 32); a5 += __shfl_xor(a5, 32);
    a6 += __shfl_xor(a6, 32); a7 += __shfl_xor(a7, 32);
    if (lane < 16) {
        uint4 o;
        o.x = (uint32_t)(uint16_t)f2bf(a0) | ((uint32_t)(uint16_t)f2bf(a1) << 16);
        o.y = (uint32_t)(uint16_t)f2bf(a2) | ((uint32_t)(uint16_t)f2bf(a3) << 16);
        o.z = (uint32_t)(uint16_t)f2bf(a4) | ((uint32_t)(uint16_t)f2bf(a5) << 16);
        o.w = (uint32_t)(uint16_t)f2bf(a6) | ((uint32_t)(uint16_t)f2bf(a7) << 16);
        gfb128[((size_t)row * C_ + c) * (D_ / 8) + l15] = o;
    }
}

// ---------------------------------------------------------------------------
// rowgemm v4: 1024 thr (16 waves), W+G LDS-resident, no main-loop barriers.
// GEMM2 computed SWAPPED (S^T = G^T @ Z^T via mfma(Gfrag, az, acc)):
// A-frag of G^T == stored B-frag of G; B-frag of Z^T == az. Output has
// row=lane&15 -> direct 8B global stores, second Zr round-trip eliminated.
// ---------------------------------------------------------------------------
__global__ __launch_bounds__(1024, 4) void rowgemm_mfma_kernel(
    const short* __restrict__ gfb, short* __restrict__ stkb,
    const short* __restrict__ Wf, const short* __restrict__ Gf,
    const float* __restrict__ critv)
{
    __shared__ short Wl[16384];
    __shared__ short Gl[16384];
    __shared__ short Zr[16][2048];

    for (int i = threadIdx.x; i < 2048; i += 1024) {
        ((short8*)Wl)[i] = ((const short8*)Wf)[i];
        ((short8*)Gl)[i] = ((const short8*)Gf)[i];
    }
    __syncthreads();

    int lane = threadIdx.x & 63, w = threadIdx.x >> 6;
    int g = lane >> 4, c15 = lane & 15;
    char* zw = (char*)&Zr[w][0];
    const int nrb = (N_ * C_ + 255) / 256;

    for (int rb = blockIdx.x; rb < nrb; rb += gridDim.x) {
        size_t r0 = (size_t)rb * 256 + (size_t)w * 16;
        if (r0 >= N_ * C_) continue;

        short8 af[4];
        #pragma unroll
        for (int q = 0; q < 4; ++q)
            af[q] = *(const short8*)(gfb + (r0 + c15) * D_ + q * 32 + g * 8);

        f32x4 acc[8];
        #pragma unroll
        for (int t = 0; t < 8; ++t) acc[t] = (f32x4){0.f, 0.f, 0.f, 0.f};
        {
            const short8* Wp = (const short8*)Wl;
            #pragma unroll
            for (int t = 0; t < 8; ++t)
                #pragma unroll
                for (int q = 0; q < 4; ++q)
                    acc[t] = __builtin_amdgcn_mfma_f32_16x16x32_bf16(
                        af[q], Wp[(t * 4 + q) * 64 + lane], acc[t], 0, 0, 0);
        }

        // scale by crit, write Z to per-wave swizzled LDS (transpose 1)
        int rbase = (int)r0 + g * 4;
        #pragma unroll
        for (int t = 0; t < 8; ++t)
            #pragma unroll
            for (int r = 0; r < 4; ++r) {
                float cv = critv[((rbase + r) % C_) * D_ + t * 16 + c15];
                float z = acc[t][r] * cv;
                int zrow = g * 4 + r;
                int cb = 32 * t + 2 * c15;
                int off = zrow * 256 + (cb ^ ((zrow & 7) << 4));
                *(short*)(zw + off) = f2bf(z);
            }

        short8 az[4];
        #pragma unroll
        for (int q = 0; q < 4; ++q) {
            int cb0 = 64 * q + 16 * g;
            int off = c15 * 256 + (cb0 ^ ((c15 & 7) << 4));
            az[q] = *(const short8*)(zw + off);
        }

        // GEMM2 swapped: acc2[t] = S^T tile -> S[row=r0+c15][col=t*16+g*4+r]
        f32x4 acc2[8];
        #pragma unroll
        for (int t = 0; t < 8; ++t) acc2[t] = (f32x4){0.f, 0.f, 0.f, 0.f};
        {
            const short8* Gp = (const short8*)Gl;
            #pragma unroll
            for (int t = 0; t < 8; ++t)
                #pragma unroll
                for (int q = 0; q < 4; ++q)
                    acc2[t] = __builtin_amdgcn_mfma_f32_16x16x32_bf16(
                        Gp[(t * 4 + q) * 64 + lane], az[q], acc2[t], 0, 0, 0);
        }

        // leaky + pack + direct 8B stores (row = r0 + c15)
        short* srow = stkb + (r0 + c15) * D_;
        #pragma unroll
        for (int t = 0; t < 8; ++t) {
            float s0 = acc2[t][0], s1 = acc2[t][1], s2 = acc2[t][2], s3 = acc2[t][3];
            s0 = s0 > 0.f ? s0 : 0.01f * s0;
            s1 = s1 > 0.f ? s1 : 0.01f * s1;
            s2 = s2 > 0.f ? s2 : 0.01f * s2;
            s3 = s3 > 0.f ? s3 : 0.01f * s3;
            uint2 o;
            o.x = (uint32_t)(uint16_t)f2bf(s0) | ((uint32_t)(uint16_t)f2bf(s1) << 16);
            o.y = (uint32_t)(uint16_t)f2bf(s2) | ((uint32_t)(uint16_t)f2bf(s3) << 16);
            *(uint2*)(srow + t * 16 + g * 4) = o;
        }
    }
}

// ---------------------------------------------------------------------------
// attn v3: A-frags direct from bf16 stkb; ego phase uint4 (5 iters)
//   l=0: egob = bf16(ego0);  l=1: bank = (init + ego0 + ego1)/3
// ---------------------------------------------------------------------------
__global__ __launch_bounds__(256, 3) void attn_mfma_kernel(
    const short* __restrict__ stkb, const short* __restrict__ P1f,
    const float* __restrict__ p2, const float* __restrict__ user,
    const float* __restrict__ item, short* __restrict__ egob,
    float* __restrict__ bank, int last)
{
    __shared__ float rawl[80 * C_];
    __shared__ float wl[80 * C_];

    int tid = threadIdx.x;
    int lane = tid & 63, w = tid >> 6;
    int g = lane >> 4, c15 = lane & 15;
    int klo = (5 * w) >> 2;

    short8 Bf[5][4];
    float p2v[5];
    #pragma unroll
    for (int i = 0; i < 5; ++i) {
        int t = 5 * w + i;
        #pragma unroll
        for (int q = 0; q < 4; ++q)
            Bf[i][q] = ((const short8*)P1f)[(t * 4 + q) * 64 + lane];
        p2v[i] = p2[(t >> 2) * A_ + (t & 3) * 16 + c15];
    }

    float4*       bank4 = (float4*)bank;
    const float4* user4 = (const float4*)user;
    const float4* item4 = (const float4*)item;

    for (int grp = blockIdx.x; grp < N_ / 16; grp += gridDim.x) {
        size_t n0 = (size_t)grp * 16;
        for (int i = tid; i < 80 * C_; i += 256) rawl[i] = 0.f;
        __syncthreads();

        for (int rt = 0; rt < 5; ++rt) {
            short8 af[4];
            #pragma unroll
            for (int q = 0; q < 4; ++q)
                af[q] = *(const short8*)(stkb + (n0 * 5 + rt * 16 + c15) * D_ + q * 32 + g * 8);

            f32x4 acc[5];
            #pragma unroll
            for (int i = 0; i < 5; ++i) acc[i] = (f32x4){0.f, 0.f, 0.f, 0.f};
            #pragma unroll
            for (int i = 0; i < 5; ++i)
                #pragma unroll
                for (int q = 0; q < 4; ++q)
                    acc[i] = __builtin_amdgcn_mfma_f32_16x16x32_bf16(
                        af[q], Bf[i][q], acc[i], 0, 0, 0);

            float2 ps[4];
            #pragma unroll
            for (int r = 0; r < 4; ++r) ps[r] = make_float2(0.f, 0.f);
            #pragma unroll
            for (int i = 0; i < 5; ++i) {
                int t = 5 * w + i;
                bool lo = (t >> 2) == klo;
                #pragma unroll
                for (int r = 0; r < 4; ++r) {
                    float x = acc[i][r];
                    float e = __expf(2.f * x);
                    float th = 1.f - 2.f * __builtin_amdgcn_rcpf(e + 1.f);
                    float con = th * p2v[i];
                    if (lo) ps[r].x += con; else ps[r].y += con;
                }
            }
            #pragma unroll
            for (int r = 0; r < 4; ++r) {
                #pragma unroll
                for (int m = 1; m < 16; m <<= 1) {
                    ps[r].x += __shfl_xor(ps[r].x, m);
                    ps[r].y += __shfl_xor(ps[r].y, m);
                }
                if (c15 == 0) {
                    int row = rt * 16 + g * 4 + r;
                    atomicAdd(&rawl[row * C_ + klo], ps[r].x);
                    atomicAdd(&rawl[row * C_ + klo + 1], ps[r].y);
                }
            }
        }
        __syncthreads();

        if (tid < 80) {
            int nl = tid / C_, k = tid % C_;
            float rv[C_];
            #pragma unroll
            for (int c = 0; c < C_; ++c) rv[c] = rawl[(nl * C_ + c) * C_ + k];
            float m = rv[0];
            #pragma unroll
            for (int c = 1; c < C_; ++c) m = fmaxf(m, rv[c]);
            float s = 0.f;
            #pragma unroll
            for (int c = 0; c < C_; ++c) { rv[c] = __expf(rv[c] - m); s += rv[c]; }
            float inv = __builtin_amdgcn_rcpf(s);
            #pragma unroll
            for (int c = 0; c < C_; ++c) wl[tid * C_ + c] = rv[c] * inv;
        }
        __syncthreads();

        // ego phase: uint4 granularity (8 bf16 per item), 1280 items
        #pragma unroll
        for (int ii = 0; ii < 5; ++ii) {
            int idx = tid + 256 * ii;
            int f8 = idx & 15;
            int nl = (idx >> 4) & 15, k = idx >> 8;
            float e[8] = {0.f, 0.f, 0.f, 0.f, 0.f, 0.f, 0.f, 0.f};
            #pragma unroll
            for (int c = 0; c < C_; ++c) {
                float wv = wl[(nl * C_ + k) * C_ + c];
                uint4 sv = ((const uint4*)(stkb + ((n0 + nl) * C_ + c) * D_))[f8];
                union { uint32_t u; float f; } t;
                t.u = sv.x << 16;         e[0] = fmaf(wv, t.f, e[0]);
                t.u = sv.x & 0xffff0000u; e[1] = fmaf(wv, t.f, e[1]);
                t.u = sv.y << 16;         e[2] = fmaf(wv, t.f, e[2]);
                t.u = sv.y & 0xffff0000u; e[3] = fmaf(wv, t.f, e[3]);
                t.u = sv.z << 16;         e[4] = fmaf(wv, t.f, e[4]);
                t.u = sv.z & 0xffff0000u; e[5] = fmaf(wv, t.f, e[5]);
                t.u = sv.w << 16;         e[6] = fmaf(wv, t.f, e[6]);
                t.u = sv.w & 0xffff0000u; e[7] = fmaf(wv, t.f, e[7]);
            }
            size_t n = n0 + nl;
            size_t go = ((n * 5 + k) * 16 + f8) * 8;      // element offset
            if (!last) {
                short8 pk;
                #pragma unroll
                for (int x = 0; x < 8; ++x) pk[x] = f2bf(e[x]);
                *(short8*)(egob + go) = pk;
            } else {
                uint4 e0 = *(const uint4*)(egob + go);
                size_t bo = (n * 5 + k) * 32 + f8 * 2;    // float4 index
                float4 b0 = (n < U_) ? user4[((size_t)n * C_ + k) * 32 + f8 * 2]
                                     : item4[((size_t)(n - U_) * C_ + k) * 32 + f8 * 2];
                float4 b1 = (n < U_) ? user4[((size_t)n * C_ + k) * 32 + f8 * 2 + 1]
                                     : item4[((size_t)(n - U_) * C_ + k) * 32 + f8 * 2 + 1];
                union { uint32_t u; float f; } t;
                t.u = e0.x << 16;         b0.x += t.f + e[0];
                t.u = e0.x & 0xffff0000u; b0.y += t.f + e[1];
                t.u = e0.y << 16;         b0.z += t.f + e[2];
                t.u = e0.y & 0xffff0000u; b0.w += t.f + e[3];
                t.u = e0.z << 16;         b1.x += t.f + e[4];
                t.u = e0.z & 0xffff0000u; b1.y += t.f + e[5];
                t.u = e0.w << 16;         b1.z += t.f + e[6];
                t.u = e0.w & 0xffff0000u; b1.w += t.f + e[7];
                b0.x *= (1.f / 3.f); b0.y *= (1.f / 3.f);
                b0.z *= (1.f / 3.f); b0.w *= (1.f / 3.f);
                b1.x *= (1.f / 3.f); b1.y *= (1.f / 3.f);
                b1.z *= (1.f / 3.f); b1.w *= (1.f / 3.f);
                bank4[bo] = b0;
                bank4[bo + 1] = b1;
            }
        }
    }
}

extern "C" void kernel_launch(void* const* d_in, const int* in_sizes, int n_in,
                              void* d_out, int out_size, void* d_ws, size_t ws_size,
                              hipStream_t stream) {
    const float* user  = (const float*)d_in[0];
    const float* item  = (const float*)d_in[1];
    const float* crit0 = (const float*)d_in[2];
    const float* W     = (const float*)d_in[3];
    const float* gl    = (const float*)d_in[4];
    const float* cl    = (const float*)d_in[5];
    const float* p1    = (const float*)d_in[6];
    const float* p2    = (const float*)d_in[7];
    const float* vals  = (const float*)d_in[8];
    const int*   rows  = (const int*)d_in[9];
    const int*   cols  = (const int*)d_in[10];

    float* out  = (float*)d_out;
    float* bank = out;
    float* padrow = out + (size_t)N_ * C_ * D_;
    float* crit_means = out + (size_t)(N_ + 1) * C_ * D_;

    const size_t NCD = (size_t)N_ * C_ * D_;
    short* egob  = (short*)d_ws;                        // N*C*D bf16
    short* gfb   = egob + NCD;                          // N*C*D bf16
    short* stkb  = gfb + NCD;                           // N*C*D bf16
    float* crit1 = (float*)(stkb + NCD);
    float* crit2 = crit1 + C_ * D_;
    short* Wf    = (short*)(crit2 + C_ * D_);           // 16384 bf16
    short* Gf    = Wf + (size_t)D_ * D_;                // 2 x 16384 bf16
    short* P1f   = Gf + 2 * (size_t)D_ * D_;            // 128*320 bf16
    int* bin_start = (int*)(P1f + (size_t)D_ * C_ * A_);   // BINS_+2
    int* keyB      = bin_start + BINS_ + 2;             // NEDGE_
    uint2* vcB     = (uint2*)(keyB + NEDGE_);           // NEDGE_ (8B-aligned)
    int* ghist     = (int*)(vcB + NEDGE_);              // ND1_*NBRX_
    int* ghistT    = ghist + (size_t)ND1_ * NBRX_;      // ND1_*NBRX_
    int* bsum      = ghistT + (size_t)ND1_ * NBRX_;     // 2048
    // pass-1 scratch overlaid on stkb (dead until rowgemm)
    uint2* vcA = (uint2*)stkb;                          // NEDGE_*8B = 51.2MB
    int*  keyA = (int*)((char*)stkb + (size_t)NEDGE_ * 8);  // 25.6MB

    init_kernel<<<(int)((NCD / 8 + 255) / 256), 256, 0, stream>>>(user, item, egob);
    crit_kernel<<<1, 128, 0, stream>>>(crit0, cl, crit1, crit2, crit_means, padrow);
    prepack_kernel<<<24, 256, 0, stream>>>(W, gl, Wf, Gf);
    prepack_p1_kernel<<<80, 64, 0, stream>>>(p1, P1f);

    // ---- radix CSR build (c-major keys) ----
    const int n1 = ND1_ * NBRX_, n2 = ND2_ * NBRX_;
    p1_count_kernel<<<NBRX_, 256, 0, stream>>>(rows, ghistT);
    transpose_kernel<<<(n1 + 255) / 256, 256, 0, stream>>>(ghistT, ghist, NBRX_, ND1_);
    scanA_g<<<(n1 + 1023) / 1024, 256, 0, stream>>>(ghist, ghist, bsum, n1);
    scanB_g<<<1, 256, 0, stream>>>(bsum, (n1 + 1023) / 1024);
    scanC_g<<<(n1 + 1023) / 1024, 256, 0, stream>>>(ghist, bsum, n1);
    transpose_kernel<<<(n1 + 255) / 256, 256, 0, stream>>>(ghist, ghistT, ND1_, NBRX_);
    p1_place_kernel<<<NBRX_, 256, 0, stream>>>(rows, vals, cols, ghistT, keyA, vcA);

    p2_count_kernel<<<NBRX_, 256, 0, stream>>>(keyA, ghistT);
    transpose_kernel<<<(n2 + 255) / 256, 256, 0, stream>>>(ghistT, ghist, NBRX_, ND2_);
    scanA_g<<<(n2 + 1023) / 1024, 256, 0, stream>>>(ghist, ghist, bsum, n2);
    scanB_g<<<1, 256, 0, stream>>>(bsum, (n2 + 1023) / 1024);
    scanC_g<<<(n2 + 1023) / 1024, 256, 0, stream>>>(ghist, bsum, n2);
    transpose_kernel<<<(n2 + 255) / 256, 256, 0, stream>>>(ghist, ghistT, ND2_, NBRX_);
    p2_place_kernel<<<NBRX_, 256, 0, stream>>>(keyA, vcA, ghistT, keyB, vcB);

    boundary_kernel<<<(NEDGE_ + 255) / 256, 256, 0, stream>>>(keyB, bin_start);

    for (int l = 0; l < L_; ++l) {
        gather_kernel<<<BINS_ / 4, 256, 0, stream>>>(
            (const uint4*)egob, vcB, bin_start, (uint4*)gfb);
        rowgemm_mfma_kernel<<<256, 1024, 0, stream>>>(
            gfb, stkb, Wf, Gf + (size_t)l * D_ * D_, l == 0 ? crit0 : crit1);
        attn_mfma_kernel<<<768, 256, 0, stream>>>(
            stkb, P1f, p2, user, item, egob, bank, l == L_ - 1 ? 1 : 0);
    }
}

// Round 13
// 1263.943 us; speedup vs baseline: 1.0562x; 1.0562x over previous
//
#include <hip/hip_runtime.h>
#include <cstdint>
#include <cmath>

#define U_ 40000
#define I_ 40000
#define C_ 5
#define D_ 128
#define A_ 64
#define L_ 2
#define E_ 1280000
#define N_ (U_ + I_)
#define BINS_ (N_ * C_)
#define NEDGE_ (C_ * E_)                      // 6,400,000
#define EPB_ 4096
#define NBRX_ ((NEDGE_ + EPB_ - 1) / EPB_)    // 1563
#define ND1_ 1024
#define ND2_ 512

typedef __attribute__((ext_vector_type(8))) short short8;
typedef __attribute__((ext_vector_type(4))) short short4v;
typedef __attribute__((ext_vector_type(4))) float f32x4;

static __device__ __forceinline__ short f2bf(float f) {
    union { float f; uint32_t u; } x; x.f = f;
    uint32_t u = x.u;
    uint32_t r = (u + 0x7fffu + ((u >> 16) & 1u)) >> 16;   // RNE
    return (short)r;
}

// ---------------------------------------------------------------------------
// init: egob = bf16(concat(user, item))
// ---------------------------------------------------------------------------
__global__ __launch_bounds__(256) void init_kernel(
    const float* __restrict__ user, const float* __restrict__ item,
    short* __restrict__ egob)
{
    size_t i = (size_t)blockIdx.x * 256 + threadIdx.x;    // 8-float index
    const size_t total8 = (size_t)N_ * C_ * D_ / 8;
    const size_t user4  = (size_t)U_ * C_ * D_ / 4;
    if (i < total8) {
        size_t f4 = 2 * i;
        const float4* src = (f4 < user4) ? (const float4*)user
                                         : (const float4*)item - user4;
        float4 x0 = src[f4], x1 = src[f4 + 1];
        short8 p;
        p[0] = f2bf(x0.x); p[1] = f2bf(x0.y); p[2] = f2bf(x0.z); p[3] = f2bf(x0.w);
        p[4] = f2bf(x1.x); p[5] = f2bf(x1.y); p[6] = f2bf(x1.z); p[7] = f2bf(x1.w);
        ((short8*)egob)[i] = p;
    }
}

// ---------------------------------------------------------------------------
// crit chain + zero pad row of d_out
// ---------------------------------------------------------------------------
__global__ __launch_bounds__(128) void crit_kernel(
    const float* __restrict__ crit0, const float* __restrict__ clayers,
    float* __restrict__ crit1, float* __restrict__ crit2,
    float* __restrict__ crit_means, float* __restrict__ padrow)
{
    __shared__ float c0[C_ * D_], c1[C_ * D_], c2[C_ * D_];
    int t = threadIdx.x;
    for (int i = t; i < C_ * D_; i += 128) { c0[i] = crit0[i]; padrow[i] = 0.f; }
    __syncthreads();
    for (int c = 0; c < C_; ++c) {
        float acc = 0.f;
        for (int d = 0; d < D_; ++d) acc = fmaf(c0[c * D_ + d], clayers[d * D_ + t], acc);
        c1[c * D_ + t] = acc;
    }
    __syncthreads();
    for (int c = 0; c < C_; ++c) {
        float acc = 0.f;
        for (int d = 0; d < D_; ++d) acc = fmaf(c1[c * D_ + d], clayers[D_ * D_ + d * D_ + t], acc);
        c2[c * D_ + t] = acc;
    }
    __syncthreads();
    for (int i = t; i < C_ * D_; i += 128) {
        crit1[i] = c1[i];
        crit2[i] = c2[i];
        crit_means[i] = (c0[i] + c1[i] + c2[i]) * (1.0f / 3.0f);
    }
}

// ---------------------------------------------------------------------------
// prepack W / G0 / G1 into bf16 B-fragment layout (mfma_f32_16x16x32_bf16)
// ---------------------------------------------------------------------------
__global__ __launch_bounds__(256) void prepack_kernel(
    const float* __restrict__ W, const float* __restrict__ gl,
    short* __restrict__ Wf, short* __restrict__ Gf)
{
    int b = blockIdx.x;               // 0..23: matrix = b>>3, t = b&7
    int m = b >> 3, t = b & 7;
    int q = threadIdx.x >> 6, l = threadIdx.x & 63;
    int g = l >> 4, c15 = l & 15;
    const float* src = (m == 0) ? W : gl + (size_t)(m - 1) * D_ * D_;
    short*       dst = (m == 0) ? Wf : Gf + (size_t)(m - 1) * D_ * D_;
    short8 v;
    #pragma unroll
    for (int j = 0; j < 8; ++j) {
        int k = q * 32 + g * 8 + j;
        int n = t * 16 + c15;
        v[j] = f2bf(src[k * D_ + n]);
    }
    *(short8*)(dst + (((t * 4 + q) * 64 + l) << 3)) = v;
}

// ---------------------------------------------------------------------------
// prepack p1 (C,D,A) as B-frags of P1all (128 x 320)
// ---------------------------------------------------------------------------
__global__ __launch_bounds__(64) void prepack_p1_kernel(
    const float* __restrict__ p1, short* __restrict__ P1f)
{
    int t = blockIdx.x >> 2, q = blockIdx.x & 3;   // 80 blocks
    int lane = threadIdx.x;
    int g = lane >> 4, c15 = lane & 15;
    int k = t >> 2, a = (t & 3) * 16 + c15;
    short8 v;
    #pragma unroll
    for (int j = 0; j < 8; ++j) {
        int d = q * 32 + g * 8 + j;
        v[j] = f2bf(p1[((size_t)k * D_ + d) * A_ + a]);
    }
    *(short8*)(P1f + (((t * 4 + q) * 64 + lane) << 3)) = v;
}

// ===========================================================================
// CSR build via 2-pass LSD radix sort (no global atomics)
// key = bin' = c*N + row (c-major). pass1: low 10 bits (non-stable),
// pass2: high 9 bits (stable via ballot ranks). Then boundary -> bin_start.
// Counts from the count kernels are SAVED (gcntT) so place kernels skip
// their own counting pass.
// ===========================================================================

__global__ __launch_bounds__(256) void p1_count_kernel(
    const int* __restrict__ rows, int* __restrict__ ghistT,
    int* __restrict__ gcntT)
{
    __shared__ int h[ND1_];
    int b = blockIdx.x, tid = threadIdx.x;
    for (int i = tid; i < ND1_; i += 256) h[i] = 0;
    __syncthreads();
    int base = b * EPB_;
    for (int ch = 0; ch < EPB_ / 256; ++ch) {
        int eid = base + ch * 256 + tid;
        if (eid < NEDGE_) {
            int key = (eid / E_) * N_ + rows[eid];
            atomicAdd(&h[key & (ND1_ - 1)], 1);
        }
    }
    __syncthreads();
    for (int i = tid; i < ND1_; i += 256) {
        ghistT[b * ND1_ + i] = h[i];
        gcntT[b * ND1_ + i] = h[i];
    }
}

__global__ __launch_bounds__(256) void transpose_kernel(
    const int* __restrict__ src, int* __restrict__ dst, int R, int Cc)
{
    int i = blockIdx.x * 256 + threadIdx.x;
    if (i < R * Cc) { int r = i / Cc, c = i % Cc; dst[c * R + r] = src[i]; }
}

__global__ __launch_bounds__(256) void scanA_g(
    const int* __restrict__ src, int* __restrict__ dst,
    int* __restrict__ bsum, int n)
{
    __shared__ int ls[256];
    int b = blockIdx.x, t = threadIdx.x;
    int base = b * 1024 + t * 4;
    int v[4];
    #pragma unroll
    for (int i = 0; i < 4; ++i) v[i] = (base + i < n) ? src[base + i] : 0;
    int s = v[0] + v[1] + v[2] + v[3];
    ls[t] = s;
    __syncthreads();
    for (int off = 1; off < 256; off <<= 1) {
        int x = (t >= off) ? ls[t - off] : 0;
        __syncthreads();
        ls[t] += x;
        __syncthreads();
    }
    int excl = ls[t] - s;
    if (t == 255) bsum[b] = ls[255];
    #pragma unroll
    for (int i = 0; i < 4; ++i) {
        if (base + i < n) dst[base + i] = excl;
        excl += v[i];
    }
}

__global__ __launch_bounds__(256) void scanB_g(int* __restrict__ bsum, int nb)
{
    __shared__ int ls[256];
    int t = threadIdx.x;
    int v[8]; int s = 0;
    #pragma unroll
    for (int i = 0; i < 8; ++i) {
        int idx = t * 8 + i;
        v[i] = (idx < nb) ? bsum[idx] : 0;
        s += v[i];
    }
    ls[t] = s;
    __syncthreads();
    for (int off = 1; off < 256; off <<= 1) {
        int x = (t >= off) ? ls[t - off] : 0;
        __syncthreads();
        ls[t] += x;
        __syncthreads();
    }
    int excl = ls[t] - s;
    #pragma unroll
    for (int i = 0; i < 8; ++i) {
        int idx = t * 8 + i;
        if (idx < nb) bsum[idx] = excl;
        excl += v[i];
    }
}

__global__ __launch_bounds__(256) void scanC_g(
    int* __restrict__ dst, const int* __restrict__ bsum, int n)
{
    int b = blockIdx.x, t = threadIdx.x;
    int off = bsum[b];
    int base = b * 1024 + t * 4;
    #pragma unroll
    for (int i = 0; i < 4; ++i)
        if (base + i < n) dst[base + i] += off;
}

// pass1 place: counts preloaded from gcntT (no re-count pass)
__global__ __launch_bounds__(256) void p1_place_kernel(
    const int* __restrict__ rows, const float* __restrict__ vals,
    const int* __restrict__ cols, const int* __restrict__ gbaseT,
    const int* __restrict__ gcntT,
    int* __restrict__ keyA, uint2* __restrict__ vcA)
{
    __shared__ int cur[ND1_];
    __shared__ int bst[ND1_];
    __shared__ int gb[ND1_];
    __shared__ int ts[256];
    __shared__ int sK[EPB_];
    __shared__ uint2 sV[EPB_];
    int b = blockIdx.x, tid = threadIdx.x;
    for (int i = tid; i < ND1_; i += 256) gb[i] = gbaseT[b * ND1_ + i];
    // scan preloaded counts -> bst; cur = bst
    {
        int v[4]; int s = 0;
        #pragma unroll
        for (int i = 0; i < 4; ++i) { v[i] = gcntT[b * ND1_ + tid * 4 + i]; s += v[i]; }
        ts[tid] = s;
        __syncthreads();
        for (int off = 1; off < 256; off <<= 1) {
            int x = (tid >= off) ? ts[tid - off] : 0;
            __syncthreads();
            ts[tid] += x;
            __syncthreads();
        }
        int excl = ts[tid] - s;
        #pragma unroll
        for (int i = 0; i < 4; ++i) { bst[tid * 4 + i] = excl; cur[tid * 4 + i] = excl; excl += v[i]; }
    }
    __syncthreads();
    int base = b * EPB_;
    for (int ch = 0; ch < EPB_ / 256; ++ch) {
        int eid = base + ch * 256 + tid;
        if (eid < NEDGE_) {
            int key = (eid / E_) * N_ + rows[eid];
            int d = key & (ND1_ - 1);
            int p = atomicAdd(&cur[d], 1);
            sK[p] = key;
            union { float f; uint32_t u; } t; t.f = vals[eid];
            uint2 m; m.x = t.u; m.y = (uint32_t)cols[eid];
            sV[p] = m;
        }
    }
    __syncthreads();
    int M = NEDGE_ - base; if (M > EPB_) M = EPB_;
    for (int i = tid; i < M; i += 256) {
        int key = sK[i]; int d = key & (ND1_ - 1);
        int pos = gb[d] + (i - bst[d]);
        keyA[pos] = key; vcA[pos] = sV[i];
    }
}

__global__ __launch_bounds__(256) void p2_count_kernel(
    const int* __restrict__ keyA, int* __restrict__ ghistT,
    int* __restrict__ gcntT)
{
    __shared__ int h[ND2_];
    int b = blockIdx.x, tid = threadIdx.x;
    for (int i = tid; i < ND2_; i += 256) h[i] = 0;
    __syncthreads();
    int base = b * EPB_;
    for (int ch = 0; ch < EPB_ / 256; ++ch) {
        int eid = base + ch * 256 + tid;
        if (eid < NEDGE_) atomicAdd(&h[keyA[eid] >> 10], 1);
    }
    __syncthreads();
    for (int i = tid; i < ND2_; i += 256) {
        ghistT[b * ND2_ + i] = h[i];
        gcntT[b * ND2_ + i] = h[i];
    }
}

// pass2 place: STABLE via wave ballot ranks; counts preloaded; 3 syncs/chunk
__global__ __launch_bounds__(256) void p2_place_kernel(
    const int* __restrict__ keyA, const uint2* __restrict__ vcA,
    const int* __restrict__ gbaseT, const int* __restrict__ gcntT,
    int* __restrict__ keyB, uint2* __restrict__ vcB)
{
    __shared__ int cur[ND2_];
    __shared__ int bst[ND2_];
    __shared__ int gb[ND2_];
    __shared__ int wh[4 * ND2_];
    __shared__ int ts[256];
    __shared__ int sK[EPB_];
    __shared__ uint2 sV[EPB_];
    int b = blockIdx.x, tid = threadIdx.x;
    int lane = tid & 63, wv = tid >> 6;
    for (int i = tid; i < ND2_; i += 256) gb[i] = gbaseT[b * ND2_ + i];
    for (int i = tid; i < 4 * ND2_; i += 256) wh[i] = 0;
    {
        int v0 = gcntT[b * ND2_ + tid * 2], v1 = gcntT[b * ND2_ + tid * 2 + 1];
        int s = v0 + v1;
        ts[tid] = s;
        __syncthreads();
        for (int off = 1; off < 256; off <<= 1) {
            int x = (tid >= off) ? ts[tid - off] : 0;
            __syncthreads();
            ts[tid] += x;
            __syncthreads();
        }
        int excl = ts[tid] - s;
        bst[tid * 2] = excl; bst[tid * 2 + 1] = excl + v0;
        cur[tid * 2] = excl; cur[tid * 2 + 1] = excl + v0;
    }
    __syncthreads();
    int base = b * EPB_;
    for (int ch = 0; ch < EPB_ / 256; ++ch) {
        int eid = base + ch * 256 + tid;
        bool valid = eid < NEDGE_;
        int key = 0, d = 0; uint2 v = make_uint2(0u, 0u);
        if (valid) { key = keyA[eid]; v = vcA[eid]; d = key >> 10; }
        unsigned long long m = __ballot(valid ? 1 : 0);
        #pragma unroll
        for (int bit = 0; bit < 9; ++bit) {
            unsigned long long bb = __ballot((valid && ((d >> bit) & 1)) ? 1 : 0);
            m &= ((d >> bit) & 1) ? bb : ~bb;
        }
        unsigned long long ltm = ((unsigned long long)1 << lane) - 1;
        int rw = __popcll(m & ltm);
        int cnt = __popcll(m);
        if (valid && rw == 0) wh[wv * ND2_ + d] = cnt;
        __syncthreads();
        if (valid) {
            int off = 0;
            for (int w2 = 0; w2 < wv; ++w2) off += wh[w2 * ND2_ + d];
            int p = cur[d] + off + rw;
            sK[p] = key; sV[p] = v;
        }
        __syncthreads();
        for (int i = tid; i < ND2_; i += 256) {
            cur[i] += wh[i] + wh[ND2_ + i] + wh[2 * ND2_ + i] + wh[3 * ND2_ + i];
            wh[i] = 0; wh[ND2_ + i] = 0; wh[2 * ND2_ + i] = 0; wh[3 * ND2_ + i] = 0;
        }
        __syncthreads();
    }
    int M = NEDGE_ - base; if (M > EPB_) M = EPB_;
    for (int i = tid; i < M; i += 256) {
        int key = sK[i]; int d = key >> 10;
        int pos = gb[d] + (i - bst[d]);
        keyB[pos] = key; vcB[pos] = sV[i];
    }
}

__global__ __launch_bounds__(256) void boundary_kernel(
    const int* __restrict__ keyB, int* __restrict__ bin_start)
{
    int i = blockIdx.x * 256 + threadIdx.x;
    if (i >= NEDGE_) return;
    int k = keyB[i];
    if (i == 0) {
        for (int b = 0; b <= k; ++b) bin_start[b] = 0;
    } else {
        int kp = keyB[i - 1];
        for (int b = kp + 1; b <= k; ++b) bin_start[b] = i;
    }
    if (i == NEDGE_ - 1) {
        for (int b = k + 1; b <= BINS_; ++b) bin_start[b] = NEDGE_;
    }
}

// ---------------------------------------------------------------------------
// gather (bf16) quarter-wave (R11 form): 16-lane quarter owns one edge; lane
// reads uint4 (16B = 8 dims). 16-edge main step -> 4 independent loads in
// flight; metadata staged via lanes + shfl. 2-level cross-quarter reduce.
// ---------------------------------------------------------------------------
__global__ __launch_bounds__(256) void gather_kernel(
    const uint4* __restrict__ eg128, const uint2* __restrict__ vc,
    const int* __restrict__ bin_start, uint4* __restrict__ gfb128)
{
    int w = (int)(((size_t)blockIdx.x * 256 + threadIdx.x) >> 6);
    int lane = threadIdx.x & 63;
    w = __builtin_amdgcn_readfirstlane(w);
    int bs = bin_start[w], be = bin_start[w + 1];
    int c = w / N_;
    int row = w - c * N_;
    int q4 = lane >> 4, l15 = lane & 15;
    float a0 = 0.f, a1 = 0.f, a2 = 0.f, a3 = 0.f;
    float a4 = 0.f, a5 = 0.f, a6 = 0.f, a7 = 0.f;

    for (int base = bs; base < be; base += 64) {
        int cnt = be - base; if (cnt > 64) cnt = 64;
        float v = 0.f; int s = 0;
        if (lane < cnt) {
            uint2 m = vc[base + lane];
            union { uint32_t u; float f; } t; t.u = m.x;
            v = t.f; s = (int)m.y;
        }
        int j = 0;
        for (; j + 16 <= cnt; j += 16) {     // 16 edges: 4 loads in flight/lane
            float v0 = __shfl(v, j + q4),      v1 = __shfl(v, j + 4 + q4);
            float v2 = __shfl(v, j + 8 + q4),  v3 = __shfl(v, j + 12 + q4);
            int   s0 = __shfl(s, j + q4),      s1 = __shfl(s, j + 4 + q4);
            int   s2 = __shfl(s, j + 8 + q4),  s3 = __shfl(s, j + 12 + q4);
            uint4 m0 = eg128[((size_t)s0 * C_ + c) * (D_ / 8) + l15];
            uint4 m1 = eg128[((size_t)s1 * C_ + c) * (D_ / 8) + l15];
            uint4 m2 = eg128[((size_t)s2 * C_ + c) * (D_ / 8) + l15];
            uint4 m3 = eg128[((size_t)s3 * C_ + c) * (D_ / 8) + l15];
            union { uint32_t u; float f; } t;
            #define ACC8(mm, vv) \
                t.u = mm.x << 16;         a0 = fmaf(vv, t.f, a0); \
                t.u = mm.x & 0xffff0000u; a1 = fmaf(vv, t.f, a1); \
                t.u = mm.y << 16;         a2 = fmaf(vv, t.f, a2); \
                t.u = mm.y & 0xffff0000u; a3 = fmaf(vv, t.f, a3); \
                t.u = mm.z << 16;         a4 = fmaf(vv, t.f, a4); \
                t.u = mm.z & 0xffff0000u; a5 = fmaf(vv, t.f, a5); \
                t.u = mm.w << 16;         a6 = fmaf(vv, t.f, a6); \
                t.u = mm.w & 0xffff0000u; a7 = fmaf(vv, t.f, a7);
            ACC8(m0, v0) ACC8(m1, v1) ACC8(m2, v2) ACC8(m3, v3)
        }
        for (; j < cnt; j += 4) {            // padded tail (v=0 beyond cnt)
            float v0 = __shfl(v, j + q4);
            int   s0 = __shfl(s, j + q4);
            uint4 m0 = eg128[((size_t)s0 * C_ + c) * (D_ / 8) + l15];
            union { uint32_t u; float f; } t;
            ACC8(m0, v0)
            #undef ACC8
        }
    }
    a0 += __shfl_xor(a0, 16); a1 += __shfl_xor(a1, 16);
    a2 += __shfl_xor(a2, 16); a3 += __shfl_xor(a3, 16);
    a4 += __shfl_xor(a4, 16); a5 += __shfl_xor(a5, 16);
    a6 += __shfl_xor(a6, 16); a7 += __shfl_xor(a7, 16);
    a0 += __shfl_xor(a0, 32); a1 += __shfl_xor(a1, 32);
    a2 += __shfl_xor(a2, 32); a3 += __shfl_xor(a3, 32);
    a4 += __shfl_xor(a4, 32); a5 += __shfl_xor(a5, 32);
    a6 += __shfl_xor(a6, 32); a7 += __shfl_xor(a7, 32);
    if (lane < 16) {
        uint4 o;
        o.x = (uint32_t)(uint16_t)f2bf(a0) | ((uint32_t)(uint16_t)f2bf(a1) << 16);
        o.y = (uint32_t)(uint16_t)f2bf(a2) | ((uint32_t)(uint16_t)f2bf(a3) << 16);
        o.z = (uint32_t)(uint16_t)f2bf(a4) | ((uint32_t)(uint16_t)f2bf(a5) << 16);
        o.w = (uint32_t)(uint16_t)f2bf(a6) | ((uint32_t)(uint16_t)f2bf(a7) << 16);
        gfb128[((size_t)row * C_ + c) * (D_ / 8) + l15] = o;
    }
}

// ---------------------------------------------------------------------------
// rowgemm v4: 1024 thr (16 waves), W+G LDS-resident, no main-loop barriers.
// GEMM2 computed SWAPPED (S^T = G^T @ Z^T via mfma(Gfrag, az, acc)).
// ---------------------------------------------------------------------------
__global__ __launch_bounds__(1024, 4) void rowgemm_mfma_kernel(
    const short* __restrict__ gfb, short* __restrict__ stkb,
    const short* __restrict__ Wf, const short* __restrict__ Gf,
    const float* __restrict__ critv)
{
    __shared__ short Wl[16384];
    __shared__ short Gl[16384];
    __shared__ short Zr[16][2048];

    for (int i = threadIdx.x; i < 2048; i += 1024) {
        ((short8*)Wl)[i] = ((const short8*)Wf)[i];
        ((short8*)Gl)[i] = ((const short8*)Gf)[i];
    }
    __syncthreads();

    int lane = threadIdx.x & 63, w = threadIdx.x >> 6;
    int g = lane >> 4, c15 = lane & 15;
    char* zw = (char*)&Zr[w][0];
    const int nrb = (N_ * C_ + 255) / 256;

    for (int rb = blockIdx.x; rb < nrb; rb += gridDim.x) {
        size_t r0 = (size_t)rb * 256 + (size_t)w * 16;
        if (r0 >= N_ * C_) continue;

        short8 af[4];
        #pragma unroll
        for (int q = 0; q < 4; ++q)
            af[q] = *(const short8*)(gfb + (r0 + c15) * D_ + q * 32 + g * 8);

        f32x4 acc[8];
        #pragma unroll
        for (int t = 0; t < 8; ++t) acc[t] = (f32x4){0.f, 0.f, 0.f, 0.f};
        {
            const short8* Wp = (const short8*)Wl;
            #pragma unroll
            for (int t = 0; t < 8; ++t)
                #pragma unroll
                for (int q = 0; q < 4; ++q)
                    acc[t] = __builtin_amdgcn_mfma_f32_16x16x32_bf16(
                        af[q], Wp[(t * 4 + q) * 64 + lane], acc[t], 0, 0, 0);
        }

        int rbase = (int)r0 + g * 4;
        #pragma unroll
        for (int t = 0; t < 8; ++t)
            #pragma unroll
            for (int r = 0; r < 4; ++r) {
                float cv = critv[((rbase + r) % C_) * D_ + t * 16 + c15];
                float z = acc[t][r] * cv;
                int zrow = g * 4 + r;
                int cb = 32 * t + 2 * c15;
                int off = zrow * 256 + (cb ^ ((zrow & 7) << 4));
                *(short*)(zw + off) = f2bf(z);
            }

        short8 az[4];
        #pragma unroll
        for (int q = 0; q < 4; ++q) {
            int cb0 = 64 * q + 16 * g;
            int off = c15 * 256 + (cb0 ^ ((c15 & 7) << 4));
            az[q] = *(const short8*)(zw + off);
        }

        f32x4 acc2[8];
        #pragma unroll
        for (int t = 0; t < 8; ++t) acc2[t] = (f32x4){0.f, 0.f, 0.f, 0.f};
        {
            const short8* Gp = (const short8*)Gl;
            #pragma unroll
            for (int t = 0; t < 8; ++t)
                #pragma unroll
                for (int q = 0; q < 4; ++q)
                    acc2[t] = __builtin_amdgcn_mfma_f32_16x16x32_bf16(
                        Gp[(t * 4 + q) * 64 + lane], az[q], acc2[t], 0, 0, 0);
        }

        short* srow = stkb + (r0 + c15) * D_;
        #pragma unroll
        for (int t = 0; t < 8; ++t) {
            float s0 = acc2[t][0], s1 = acc2[t][1], s2 = acc2[t][2], s3 = acc2[t][3];
            s0 = s0 > 0.f ? s0 : 0.01f * s0;
            s1 = s1 > 0.f ? s1 : 0.01f * s1;
            s2 = s2 > 0.f ? s2 : 0.01f * s2;
            s3 = s3 > 0.f ? s3 : 0.01f * s3;
            uint2 o;
            o.x = (uint32_t)(uint16_t)f2bf(s0) | ((uint32_t)(uint16_t)f2bf(s1) << 16);
            o.y = (uint32_t)(uint16_t)f2bf(s2) | ((uint32_t)(uint16_t)f2bf(s3) << 16);
            *(uint2*)(srow + t * 16 + g * 4) = o;
        }
    }
}

// ---------------------------------------------------------------------------
// attn v3: A-frags direct from bf16 stkb; ego phase uint4 (5 iters)
//   l=0: egob = bf16(ego0);  l=1: bank = (init + ego0 + ego1)/3
// ---------------------------------------------------------------------------
__global__ __launch_bounds__(256, 3) void attn_mfma_kernel(
    const short* __restrict__ stkb, const short* __restrict__ P1f,
    const float* __restrict__ p2, const float* __restrict__ user,
    const float* __restrict__ item, short* __restrict__ egob,
    float* __restrict__ bank, int last)
{
    __shared__ float rawl[80 * C_];
    __shared__ float wl[80 * C_];

    int tid = threadIdx.x;
    int lane = tid & 63, w = tid >> 6;
    int g = lane >> 4, c15 = lane & 15;
    int klo = (5 * w) >> 2;

    short8 Bf[5][4];
    float p2v[5];
    #pragma unroll
    for (int i = 0; i < 5; ++i) {
        int t = 5 * w + i;
        #pragma unroll
        for (int q = 0; q < 4; ++q)
            Bf[i][q] = ((const short8*)P1f)[(t * 4 + q) * 64 + lane];
        p2v[i] = p2[(t >> 2) * A_ + (t & 3) * 16 + c15];
    }

    float4*       bank4 = (float4*)bank;
    const float4* user4 = (const float4*)user;
    const float4* item4 = (const float4*)item;

    for (int grp = blockIdx.x; grp < N_ / 16; grp += gridDim.x) {
        size_t n0 = (size_t)grp * 16;
        for (int i = tid; i < 80 * C_; i += 256) rawl[i] = 0.f;
        __syncthreads();

        for (int rt = 0; rt < 5; ++rt) {
            short8 af[4];
            #pragma unroll
            for (int q = 0; q < 4; ++q)
                af[q] = *(const short8*)(stkb + (n0 * 5 + rt * 16 + c15) * D_ + q * 32 + g * 8);

            f32x4 acc[5];
            #pragma unroll
            for (int i = 0; i < 5; ++i) acc[i] = (f32x4){0.f, 0.f, 0.f, 0.f};
            #pragma unroll
            for (int i = 0; i < 5; ++i)
                #pragma unroll
                for (int q = 0; q < 4; ++q)
                    acc[i] = __builtin_amdgcn_mfma_f32_16x16x32_bf16(
                        af[q], Bf[i][q], acc[i], 0, 0, 0);

            float2 ps[4];
            #pragma unroll
            for (int r = 0; r < 4; ++r) ps[r] = make_float2(0.f, 0.f);
            #pragma unroll
            for (int i = 0; i < 5; ++i) {
                int t = 5 * w + i;
                bool lo = (t >> 2) == klo;
                #pragma unroll
                for (int r = 0; r < 4; ++r) {
                    float x = acc[i][r];
                    float e = __expf(2.f * x);
                    float th = 1.f - 2.f * __builtin_amdgcn_rcpf(e + 1.f);
                    float con = th * p2v[i];
                    if (lo) ps[r].x += con; else ps[r].y += con;
                }
            }
            #pragma unroll
            for (int r = 0; r < 4; ++r) {
                #pragma unroll
                for (int m = 1; m < 16; m <<= 1) {
                    ps[r].x += __shfl_xor(ps[r].x, m);
                    ps[r].y += __shfl_xor(ps[r].y, m);
                }
                if (c15 == 0) {
                    int row = rt * 16 + g * 4 + r;
                    atomicAdd(&rawl[row * C_ + klo], ps[r].x);
                    atomicAdd(&rawl[row * C_ + klo + 1], ps[r].y);
                }
            }
        }
        __syncthreads();

        if (tid < 80) {
            int nl = tid / C_, k = tid % C_;
            float rv[C_];
            #pragma unroll
            for (int c = 0; c < C_; ++c) rv[c] = rawl[(nl * C_ + c) * C_ + k];
            float m = rv[0];
            #pragma unroll
            for (int c = 1; c < C_; ++c) m = fmaxf(m, rv[c]);
            float s = 0.f;
            #pragma unroll
            for (int c = 0; c < C_; ++c) { rv[c] = __expf(rv[c] - m); s += rv[c]; }
            float inv = __builtin_amdgcn_rcpf(s);
            #pragma unroll
            for (int c = 0; c < C_; ++c) wl[tid * C_ + c] = rv[c] * inv;
        }
        __syncthreads();

        #pragma unroll
        for (int ii = 0; ii < 5; ++ii) {
            int idx = tid + 256 * ii;
            int f8 = idx & 15;
            int nl = (idx >> 4) & 15, k = idx >> 8;
            float e[8] = {0.f, 0.f, 0.f, 0.f, 0.f, 0.f, 0.f, 0.f};
            #pragma unroll
            for (int c = 0; c < C_; ++c) {
                float wv = wl[(nl * C_ + k) * C_ + c];
                uint4 sv = ((const uint4*)(stkb + ((n0 + nl) * C_ + c) * D_))[f8];
                union { uint32_t u; float f; } t;
                t.u = sv.x << 16;         e[0] = fmaf(wv, t.f, e[0]);
                t.u = sv.x & 0xffff0000u; e[1] = fmaf(wv, t.f, e[1]);
                t.u = sv.y << 16;         e[2] = fmaf(wv, t.f, e[2]);
                t.u = sv.y & 0xffff0000u; e[3] = fmaf(wv, t.f, e[3]);
                t.u = sv.z << 16;         e[4] = fmaf(wv, t.f, e[4]);
                t.u = sv.z & 0xffff0000u; e[5] = fmaf(wv, t.f, e[5]);
                t.u = sv.w << 16;         e[6] = fmaf(wv, t.f, e[6]);
                t.u = sv.w & 0xffff0000u; e[7] = fmaf(wv, t.f, e[7]);
            }
            size_t n = n0 + nl;
            size_t go = ((n * 5 + k) * 16 + f8) * 8;      // element offset
            if (!last) {
                short8 pk;
                #pragma unroll
                for (int x = 0; x < 8; ++x) pk[x] = f2bf(e[x]);
                *(short8*)(egob + go) = pk;
            } else {
                uint4 e0 = *(const uint4*)(egob + go);
                size_t bo = (n * 5 + k) * 32 + f8 * 2;    // float4 index
                float4 b0 = (n < U_) ? user4[((size_t)n * C_ + k) * 32 + f8 * 2]
                                     : item4[((size_t)(n - U_) * C_ + k) * 32 + f8 * 2];
                float4 b1 = (n < U_) ? user4[((size_t)n * C_ + k) * 32 + f8 * 2 + 1]
                                     : item4[((size_t)(n - U_) * C_ + k) * 32 + f8 * 2 + 1];
                union { uint32_t u; float f; } t;
                t.u = e0.x << 16;         b0.x += t.f + e[0];
                t.u = e0.x & 0xffff0000u; b0.y += t.f + e[1];
                t.u = e0.y << 16;         b0.z += t.f + e[2];
                t.u = e0.y & 0xffff0000u; b0.w += t.f + e[3];
                t.u = e0.z << 16;         b1.x += t.f + e[4];
                t.u = e0.z & 0xffff0000u; b1.y += t.f + e[5];
                t.u = e0.w << 16;         b1.z += t.f + e[6];
                t.u = e0.w & 0xffff0000u; b1.w += t.f + e[7];
                b0.x *= (1.f / 3.f); b0.y *= (1.f / 3.f);
                b0.z *= (1.f / 3.f); b0.w *= (1.f / 3.f);
                b1.x *= (1.f / 3.f); b1.y *= (1.f / 3.f);
                b1.z *= (1.f / 3.f); b1.w *= (1.f / 3.f);
                bank4[bo] = b0;
                bank4[bo + 1] = b1;
            }
        }
    }
}

extern "C" void kernel_launch(void* const* d_in, const int* in_sizes, int n_in,
                              void* d_out, int out_size, void* d_ws, size_t ws_size,
                              hipStream_t stream) {
    const float* user  = (const float*)d_in[0];
    const float* item  = (const float*)d_in[1];
    const float* crit0 = (const float*)d_in[2];
    const float* W     = (const float*)d_in[3];
    const float* gl    = (const float*)d_in[4];
    const float* cl    = (const float*)d_in[5];
    const float* p1    = (const float*)d_in[6];
    const float* p2    = (const float*)d_in[7];
    const float* vals  = (const float*)d_in[8];
    const int*   rows  = (const int*)d_in[9];
    const int*   cols  = (const int*)d_in[10];

    float* out  = (float*)d_out;
    float* bank = out;
    float* padrow = out + (size_t)N_ * C_ * D_;
    float* crit_means = out + (size_t)(N_ + 1) * C_ * D_;

    const size_t NCD = (size_t)N_ * C_ * D_;
    short* egob  = (short*)d_ws;                        // N*C*D bf16
    short* gfb   = egob + NCD;                          // N*C*D bf16
    short* stkb  = gfb + NCD;                           // N*C*D bf16
    float* crit1 = (float*)(stkb + NCD);
    float* crit2 = crit1 + C_ * D_;
    short* Wf    = (short*)(crit2 + C_ * D_);           // 16384 bf16
    short* Gf    = Wf + (size_t)D_ * D_;                // 2 x 16384 bf16
    short* P1f   = Gf + 2 * (size_t)D_ * D_;            // 128*320 bf16
    int* bin_start = (int*)(P1f + (size_t)D_ * C_ * A_);   // BINS_+2
    int* keyB      = bin_start + BINS_ + 2;             // NEDGE_
    uint2* vcB     = (uint2*)(keyB + NEDGE_);           // NEDGE_ (8B-aligned)
    int* ghist     = (int*)(vcB + NEDGE_);              // ND1_*NBRX_
    int* ghistT    = ghist + (size_t)ND1_ * NBRX_;      // ND1_*NBRX_
    int* bsum      = ghistT + (size_t)ND1_ * NBRX_;     // 2048
    int* gcntT     = bsum + 2048;                       // ND1_*NBRX_ (counts copy)
    // pass-1 scratch overlaid on stkb (dead until rowgemm)
    uint2* vcA = (uint2*)stkb;                          // NEDGE_*8B = 51.2MB
    int*  keyA = (int*)((char*)stkb + (size_t)NEDGE_ * 8);  // 25.6MB

    init_kernel<<<(int)((NCD / 8 + 255) / 256), 256, 0, stream>>>(user, item, egob);
    crit_kernel<<<1, 128, 0, stream>>>(crit0, cl, crit1, crit2, crit_means, padrow);
    prepack_kernel<<<24, 256, 0, stream>>>(W, gl, Wf, Gf);
    prepack_p1_kernel<<<80, 64, 0, stream>>>(p1, P1f);

    // ---- radix CSR build (c-major keys) ----
    const int n1 = ND1_ * NBRX_, n2 = ND2_ * NBRX_;
    p1_count_kernel<<<NBRX_, 256, 0, stream>>>(rows, ghistT, gcntT);
    transpose_kernel<<<(n1 + 255) / 256, 256, 0, stream>>>(ghistT, ghist, NBRX_, ND1_);
    scanA_g<<<(n1 + 1023) / 1024, 256, 0, stream>>>(ghist, ghist, bsum, n1);
    scanB_g<<<1, 256, 0, stream>>>(bsum, (n1 + 1023) / 1024);
    scanC_g<<<(n1 + 1023) / 1024, 256, 0, stream>>>(ghist, bsum, n1);
    transpose_kernel<<<(n1 + 255) / 256, 256, 0, stream>>>(ghist, ghistT, ND1_, NBRX_);
    p1_place_kernel<<<NBRX_, 256, 0, stream>>>(rows, vals, cols, ghistT, gcntT, keyA, vcA);

    p2_count_kernel<<<NBRX_, 256, 0, stream>>>(keyA, ghistT, gcntT);
    transpose_kernel<<<(n2 + 255) / 256, 256, 0, stream>>>(ghistT, ghist, NBRX_, ND2_);
    scanA_g<<<(n2 + 1023) / 1024, 256, 0, stream>>>(ghist, ghist, bsum, n2);
    scanB_g<<<1, 256, 0, stream>>>(bsum, (n2 + 1023) / 1024);
    scanC_g<<<(n2 + 1023) / 1024, 256, 0, stream>>>(ghist, bsum, n2);
    transpose_kernel<<<(n2 + 255) / 256, 256, 0, stream>>>(ghist, ghistT, ND2_, NBRX_);
    p2_place_kernel<<<NBRX_, 256, 0, stream>>>(keyA, vcA, ghistT, gcntT, keyB, vcB);

    boundary_kernel<<<(NEDGE_ + 255) / 256, 256, 0, stream>>>(keyB, bin_start);

    for (int l = 0; l < L_; ++l) {
        gather_kernel<<<BINS_ / 4, 256, 0, stream>>>(
            (const uint4*)egob, vcB, bin_start, (uint4*)gfb);
        rowgemm_mfma_kernel<<<256, 1024, 0, stream>>>(
            gfb, stkb, Wf, Gf + (size_t)l * D_ * D_, l == 0 ? crit0 : crit1);
        attn_mfma_kernel<<<768, 256, 0, stream>>>(
            stkb, P1f, p2, user, item, egob, bank, l == L_ - 1 ? 1 : 0);
    }
}